// Round 9
// baseline (584.463 us; speedup 1.0000x reference)
//
#include <hip/hip_runtime.h>

// ============================================================================
// InheritedFullyConnectedFlexiLayerSizeArchCore: hypernetwork (caseNN) +
// per-case 4-layer dynamic MLP with skip connection.
//
// R8 (single-variable: k_gemm only; rest byte-identical to R7-validated):
//  - k_gemm v3: BM=128 x BN=256 (A traffic halved, grid 1024 = 2 exact CU
//    rounds), 512 thr / 8 waves (2x4), BK=32, 3-slot counted vmcnt(6/3/0)
//    pipeline (same validated barrier scheme), T2 both-sides source-swizzle
//    (gl_lds linear dest + XOR'd global source + XOR'd ds_read: 8-way bank
//    conflict -> 2-way free), T5 setprio around MFMA cluster.
//  - Baselines: R4 simple gemm ~108us inferred; R7 total 579.7us with
//    fills at 160us crowding top-5 (gemm counters invisible).
// ============================================================================

typedef __bf16 bf16;
typedef __bf16 bf16x4 __attribute__((ext_vector_type(4)));
typedef __bf16 bf16x8 __attribute__((ext_vector_type(8)));
typedef _Float16 f16;
typedef _Float16 f16x8 __attribute__((ext_vector_type(8)));
typedef float  f32x4  __attribute__((ext_vector_type(4)));
typedef unsigned short u16x8 __attribute__((ext_vector_type(8)));

#define AS1 __attribute__((address_space(1)))
#define AS3 __attribute__((address_space(3)))

__device__ __forceinline__ void gl2lds16(const void* g, void* l) {
  // 16B-wide async global->LDS. Global src addr is PER-LANE; LDS dest is
  // wave-uniform base + lane*16 (m104/m173).
  __builtin_amdgcn_global_load_lds((const AS1 unsigned int*)g,
                                   (AS3 unsigned int*)l, 16, 0, 0);
}

__device__ __forceinline__ float silu_f(float v) {
  return v / (1.0f + __expf(-v));
}

// ---------------------------------------------------------------------------
// ht[hh][c] (f32, for k_genb) and hb16[c][hh] (f16, A-operand for k_genw).
// ---------------------------------------------------------------------------
__global__ void k_hyper(const float* __restrict__ o, const float* __restrict__ Wc,
                        const float* __restrict__ bc, float* __restrict__ ht,
                        f16* __restrict__ hb16) {
  __shared__ float os[64];
  int c = blockIdx.x;       // 64 cases
  int j = threadIdx.x;      // 256 hidden units
  if (j < 64) os[j] = o[c * 64 + j];
  __syncthreads();
  float a = bc[j];
#pragma unroll
  for (int i = 0; i < 64; ++i) a = fmaf(os[i], Wc[i * 256 + j], a);
  float h = silu_f(a);
  ht[j * 64 + c] = h;
  hb16[c * 256 + j] = (f16)h;
}

// ---------------------------------------------------------------------------
// x -> bf16
// ---------------------------------------------------------------------------
__global__ void k_xcast(const float* __restrict__ x, bf16* __restrict__ xb) {
  int i = (blockIdx.x * 256 + threadIdx.x) * 4;
  float4 v = *(const float4*)(x + i);
  bf16x4 r = { (bf16)v.x, (bf16)v.y, (bf16)v.z, (bf16)v.w };
  *(bf16x4*)(xb + i) = r;
}

// ---------------------------------------------------------------------------
// k_genw: wnat[(l*64+c)][d] = bf16( sum_hh h[c][hh]*Ww[l][hh][d] + bw[l][d] )
// MFMA-f16. Block (512 thr, 8 waves) owns layer l, d-tile of 256, full K=256.
// (unchanged from R7 — validated this round, absmax 0.0156)
// ---------------------------------------------------------------------------
__global__ __launch_bounds__(512, 1) void k_genw(
    const float* __restrict__ Ww, const float* __restrict__ bw,
    const f16* __restrict__ hb16, bf16* __restrict__ wnat) {
  __shared__ __attribute__((aligned(16))) char Hs[32768];        // h16 [64][256] swz
  __shared__ __attribute__((aligned(16))) char Wslot[3][32768];  // Ww [32][256] f32
  int l = blockIdx.x >> 8;             // 4 layers x 256 d-tiles
  int d0 = (blockIdx.x & 255) * 256;
  const float* Wwl = Ww + (size_t)l * 16777216;
  int tid = threadIdx.x, lane = tid & 63, wid = tid >> 6;

  // stage h16 (2048 16B chunks; coalesced reads, swizzled ds_write)
  for (int q = tid; q < 2048; q += 512) {
    int c = q >> 5, g = q & 31;
    f16x8 v = *(const f16x8*)(hb16 + c * 256 + g * 8);
    *(f16x8*)(Hs + c * 512 + ((g ^ (c & 7)) << 4)) = v;
  }
  __syncthreads();   // also drains vmcnt(0) -> manual counts below are exact

  auto STAGE = [&](int s, int t) {
#pragma unroll
    for (int ii = 0; ii < 4; ++ii) {
      int row = wid * 4 + ii;          // 32 rows, 1KB each
      gl2lds16(Wwl + (size_t)(t * 32 + row) * 65536 + d0 + lane * 4,
               &Wslot[s][row * 1024]);
    }
  };

  f32x4 acc[4][2] = {};
  STAGE(0, 0);
  STAGE(1, 1);
#pragma unroll
  for (int kk = 0; kk < 8; ++kk) {
    if (kk < 6) STAGE((kk + 2) % 3, kk + 2);
    if (kk < 6)       asm volatile("s_waitcnt vmcnt(8)" ::: "memory");
    else if (kk == 6) asm volatile("s_waitcnt vmcnt(4)" ::: "memory");
    else              asm volatile("s_waitcnt vmcnt(0)" ::: "memory");
    __builtin_amdgcn_s_barrier();      // slot kk%3 landed for all waves
    __builtin_amdgcn_sched_barrier(0);

    f16x8 af[4];
    int kc = kk * 4 + (lane >> 4);     // 16B chunk index along hh
#pragma unroll
    for (int mf = 0; mf < 4; ++mf) {
      int c = mf * 16 + (lane & 15);
      af[mf] = *(const f16x8*)(Hs + c * 512 + ((kc ^ (c & 7)) << 4));
    }
    const float* Ws = (const float*)&Wslot[kk % 3][0];
    f16x8 bfrag[2];
#pragma unroll
    for (int nf = 0; nf < 2; ++nf) {
      int n = wid * 32 + nf * 16 + (lane & 15);
#pragma unroll
      for (int j = 0; j < 8; ++j)
        bfrag[nf][j] = (f16)Ws[((lane >> 4) * 8 + j) * 256 + n];
    }
    asm volatile("s_waitcnt lgkmcnt(0)" ::: "memory");
    __builtin_amdgcn_sched_barrier(0); // rule 18
    __builtin_amdgcn_s_barrier();      // all reads done; next stage may write
#pragma unroll
    for (int mf = 0; mf < 4; ++mf)
#pragma unroll
      for (int nf = 0; nf < 2; ++nf)
        acc[mf][nf] = __builtin_amdgcn_mfma_f32_16x16x32_f16(
            af[mf], bfrag[nf], acc[mf][nf], 0, 0, 0);
  }

  // epilogue: C row=(lane>>4)*4+r (c), col=lane&15 (d) — HW-confirmed map
#pragma unroll
  for (int nf = 0; nf < 2; ++nf) {
    int d = d0 + wid * 32 + nf * 16 + (lane & 15);
    float bv = bw[(size_t)l * 65536 + d];
#pragma unroll
    for (int mf = 0; mf < 4; ++mf) {
      int cb = mf * 16 + (lane >> 4) * 4;
#pragma unroll
      for (int r = 0; r < 4; ++r)
        wnat[(size_t)(l * 64 + cb + r) * 65536 + d] = (bf16)(acc[mf][nf][r] + bv);
    }
  }
}

// ---------------------------------------------------------------------------
// bias[(l*64+c)][oo] = sum_hh ht[hh][c]*Wb[l][hh][oo] + bb[l][oo]
// ---------------------------------------------------------------------------
__global__ void k_genb(const float* __restrict__ Wb, const float* __restrict__ bb,
                       const float* __restrict__ ht, float* __restrict__ bias) {
  __shared__ float red[4][256];
  int l = blockIdx.x >> 6;          // 4 layers x 64 cases
  int c = blockIdx.x & 63;
  int q = threadIdx.x >> 8;         // hh quarter
  int oo = threadIdx.x & 255;
  const float* wp = Wb + (size_t)l * 65536 + oo;
  float a = 0.f;
#pragma unroll 4
  for (int hh = q * 64; hh < q * 64 + 64; ++hh)
    a = fmaf(ht[hh * 64 + c], wp[hh * 256], a);
  red[q][oo] = a;
  __syncthreads();
  if (q == 0)
    bias[(size_t)(l * 64 + c) * 256 + oo] =
        red[0][oo] + red[1][oo] + red[2][oo] + red[3][oo] + bb[l * 256 + oo];
}

// ---------------------------------------------------------------------------
// wt[(l*64+c)][o][i] = wnat[(l*64+c)][i][o]   (64x64 LDS-tiled transpose)
// (unchanged, HW-validated)
// ---------------------------------------------------------------------------
__global__ void k_tw(const unsigned short* __restrict__ w,
                     unsigned short* __restrict__ wt) {
  __shared__ __attribute__((aligned(16))) unsigned short T[64][64];
  int b = blockIdx.x;               // 256 (l,c) x 16 tiles
  int lc = b >> 4, tile = b & 15;
  int i0 = (tile >> 2) << 6, o0 = (tile & 3) << 6;
  const unsigned short* src = w + (size_t)lc * 65536;
  unsigned short* dst = wt + (size_t)lc * 65536;
  int t = threadIdx.x;
  for (int q = t; q < 512; q += 256) {
    int r = q >> 3, cc = q & 7;     // src row i0+r, o-chunk cc
    u16x8 v = *(const u16x8*)(src + (size_t)(i0 + r) * 256 + o0 + cc * 8);
    *(u16x8*)&T[r][(cc ^ ((r >> 3) & 7)) * 8] = v;
  }
  __syncthreads();
  for (int q = t; q < 512; q += 256) {
    int r = q >> 3, cc = q & 7;     // out row o0+r, i-chunk cc
    u16x8 v;
#pragma unroll
    for (int e = 0; e < 8; ++e) {
      int il = cc * 8 + e;
      v[e] = T[il][((((r >> 3) ^ (il >> 3)) & 7) << 3) + (r & 7)];
    }
    *(u16x8*)(dst + (size_t)(o0 + r) * 256 + i0 + cc * 8) = v;
  }
}

// ---------------------------------------------------------------------------
// Batched GEMM v3: Y[c] = epilogue( A[c][2048x256] @ W_t[c]^T + bias[c] )
//   BM=128, BN=256 (full N: A read once), BK=32, 8 K-iters.
//   512 thr / 8 waves (2 wm x 4 wn), each wave 64x64 out = 4x4 16x16 frags.
//   LDS layout per tile row: 64B (32 bf16); T2 source-swizzle kc^=(row>>1)&3
//   applied on BOTH gl_lds global source and ds_read (rule 21) -> frag reads
//   2-way instead of 8-way banked. 3-slot counted vmcnt(6/3/0) pipeline,
//   raw s_barrier + rule-18 fences (scheme validated in R7), T5 setprio.
// LAYER 0/1: silu -> bf16. LAYER 2: silu + skip (in-place, self-element).
// LAYER 3: identity -> fp32 d_out.
// ---------------------------------------------------------------------------
template <int LAYER>
__global__ __launch_bounds__(512, 2) void k_gemm(
    const bf16* __restrict__ A_base, const bf16* __restrict__ WT,
    const float* __restrict__ BIAS, bf16* __restrict__ Yout,
    const bf16* __restrict__ Skip, float* __restrict__ Fout) {
  __shared__ __attribute__((aligned(16))) bf16 As[3][128 * 32];
  __shared__ __attribute__((aligned(16))) bf16 Bs[3][256 * 32];
  int bx = blockIdx.x;
  bx = (bx & 7) * 128 + (bx >> 3);      // XCD swizzle, 1024 % 8 == 0 bijective
  int c  = bx >> 4;                     // 64 cases
  int m0 = (bx & 15) << 7;              // 16 m-tiles
  int tid = threadIdx.x;
  int lane = tid & 63, wid = tid >> 6;
  int wm = wid >> 2, wn = wid & 3;      // 2 x 4 wave grid -> 64x64 per wave

  const bf16* Ab = (LAYER == 0) ? A_base : (A_base + (size_t)c * 2048 * 256);
  const bf16* Bb = WT + (size_t)c * 65536;

  int q  = (wid << 6) + lane;           // this thread's chunk id (0..511)
  int row_q = q >> 2, kc_q = q & 3;
  int skA = kc_q ^ ((row_q >> 1) & 3);  // T2 source swizzle (involution)
  int q2 = q + 512;                     // B second half (rows 128..255)
  int row_q2 = q2 >> 2;
  int skB2 = kc_q ^ ((row_q2 >> 1) & 3);

  auto STAGE = [&](int slot, int t) {
    int k0 = t * 32;
    // A: 8KB = 512 chunks, 1/thread; B: 16KB = 1024 chunks, 2/thread.
    // LDS dest linear (wave base + lane*16); global source kc XOR-swizzled.
    gl2lds16(Ab + (size_t)(m0 + row_q) * 256 + k0 + skA * 8,
             (char*)&As[slot][0] + (wid << 10));
    gl2lds16(Bb + (size_t)row_q * 256 + k0 + skA * 8,
             (char*)&Bs[slot][0] + (wid << 10));
    gl2lds16(Bb + (size_t)row_q2 * 256 + k0 + skB2 * 8,
             (char*)&Bs[slot][0] + 8192 + (wid << 10));
  };

  f32x4 acc[4][4] = {};
  STAGE(0, 0);
  STAGE(1, 1);
  int kcw = lane >> 4;                  // frag k-chunk (0..3)
#pragma unroll
  for (int kk = 0; kk < 8; ++kk) {
    if (kk < 6) STAGE((kk + 2) % 3, kk + 2);
    // 3 stage-instr/wave: outstanding 9 -> vmcnt(6) retires stage(kk); FIFO
    // makes any hoisted epilogue loads strictly conservative.
    if (kk < 6)       asm volatile("s_waitcnt vmcnt(6)" ::: "memory");
    else if (kk == 6) asm volatile("s_waitcnt vmcnt(3)" ::: "memory");
    else              asm volatile("s_waitcnt vmcnt(0)" ::: "memory");
    __builtin_amdgcn_s_barrier();       // BAR_A: all waves' slot kk%3 landed
    __builtin_amdgcn_sched_barrier(0);

    const char* Asl = (const char*)&As[kk % 3][0];
    const char* Bsl = (const char*)&Bs[kk % 3][0];
    bf16x8 af[4], bfr[4];
#pragma unroll
    for (int i = 0; i < 4; ++i) {
      int ra = wm * 64 + i * 16 + (lane & 15);
      af[i] = *(const bf16x8*)(Asl + ra * 64 + ((kcw ^ ((ra >> 1) & 3)) << 4));
      int rb = wn * 64 + i * 16 + (lane & 15);
      bfr[i] = *(const bf16x8*)(Bsl + rb * 64 + ((kcw ^ ((rb >> 1) & 3)) << 4));
    }
    asm volatile("s_waitcnt lgkmcnt(0)" ::: "memory");
    __builtin_amdgcn_sched_barrier(0);  // rule 18: pin reads before BAR_B
    __builtin_amdgcn_s_barrier();       // BAR_B: reads done; stage may overwrite
    __builtin_amdgcn_s_setprio(1);      // T5
#pragma unroll
    for (int i = 0; i < 4; ++i)
#pragma unroll
      for (int j = 0; j < 4; ++j)
        acc[i][j] = __builtin_amdgcn_mfma_f32_16x16x32_bf16(af[i], bfr[j],
                                                            acc[i][j], 0, 0, 0);
    __builtin_amdgcn_s_setprio(0);
  }

  // epilogue: D row = (lane>>4)*4 + r, col = lane&15 (m89-verified mapping)
  const float* bp = BIAS + c * 256;
#pragma unroll
  for (int i = 0; i < 4; ++i) {
    int row = m0 + wm * 64 + i * 16 + (lane >> 4) * 4;
#pragma unroll
    for (int j = 0; j < 4; ++j) {
      int col = wn * 64 + j * 16 + (lane & 15);
      float bv = bp[col];
#pragma unroll
      for (int r = 0; r < 4; ++r) {
        float v = acc[i][j][r] + bv;
        size_t idx = ((size_t)c * 2048 + (row + r)) * 256 + col;
        if (LAYER < 3) {
          float s = silu_f(v);
          if (LAYER == 2) s += (float)Skip[idx];
          Yout[idx] = (bf16)s;
        } else {
          Fout[idx] = v;
        }
      }
    }
  }
}

// ---------------------------------------------------------------------------
extern "C" void kernel_launch(void* const* d_in, const int* in_sizes, int n_in,
                              void* d_out, int out_size, void* d_ws, size_t ws_size,
                              hipStream_t stream) {
  const float* x  = (const float*)d_in[0];
  const float* o  = (const float*)d_in[1];
  const float* Wc = (const float*)d_in[2];
  const float* bc = (const float*)d_in[3];
  const float* Ww = (const float*)d_in[4];
  const float* bw = (const float*)d_in[5];
  const float* Wb = (const float*)d_in[6];
  const float* bb = (const float*)d_in[7];
  float* out = (float*)d_out;
  char* ws = (char*)d_ws;

  // --- d_ws layout (everything here is read during the final GEMM) ---
  //   wt    [0,      32M)   bf16 [l*64+c][o*256+i]
  //   buf0  [32M,    96M)   bf16 activations (y0, later y2=y2+y0)
  //   bias  [96M,  +256K)   fp32 [l*64+c][256]
  //   ht    [..,   +64K )   fp32 [256][64]
  //   xb    [..,   +1M  )   bf16 x
  //   hb16  [..,   +32K )   f16  h [64 c][256 hh]
  // --- d_out overlay (128 MiB; poisoned each call, fully rewritten by
  //     k_gemm<3>; only buffers DEAD before that write may live here) ---
  //   buf1  [0,      64M)   bf16 y1        (dead after k_gemm<2>)
  //   wnat  [64M,    96M)   bf16 natural-w (dead after k_tw)
  if (ws_size < 102072320ULL) return;  // need ~97.4 MiB scratch
  bf16*  wt   = (bf16*)(ws);
  bf16*  buf0 = (bf16*)(ws + 33554432);
  float* bias = (float*)(ws + 100663296);
  float* ht   = (float*)(ws + 100925440);
  bf16*  xb   = (bf16*)(ws + 100990976);
  f16*   hb16 = (f16*)(ws + 102039552);
  bf16*  buf1 = (bf16*)(out);
  bf16*  wnat = (bf16*)((char*)out + 67108864);

  k_hyper<<<64, 256, 0, stream>>>(o, Wc, bc, ht, hb16);
  k_xcast<<<512, 256, 0, stream>>>(x, xb);
  k_genw<<<1024, 512, 0, stream>>>(Ww, bw, hb16, wnat);
  k_genb<<<256, 1024, 0, stream>>>(Wb, bb, ht, bias);
  k_tw<<<4096, 256, 0, stream>>>((const unsigned short*)wnat, (unsigned short*)wt);

  k_gemm<0><<<1024, 512, 0, stream>>>(xb,   wt,               bias,             buf0, nullptr, nullptr);
  k_gemm<1><<<1024, 512, 0, stream>>>(buf0, wt + 1 * 4194304, bias + 1 * 16384, buf1, nullptr, nullptr);
  k_gemm<2><<<1024, 512, 0, stream>>>(buf1, wt + 2 * 4194304, bias + 2 * 16384, buf0, buf0,    nullptr);
  k_gemm<3><<<1024, 512, 0, stream>>>(buf0, wt + 3 * 4194304, bias + 3 * 16384, nullptr, nullptr, out);
}